// Round 15
// baseline (438.485 us; speedup 1.0000x reference)
//
#include <hip/hip_runtime.h>
#include <math.h>

// GraphSage GNN forward. N=100000 (div 32), E=600000, HID=128, OUT=40, G=64, L=3.
// R19 = R18 (426.2us best) + ONE launch-level change: gemm grid 768 -> 512
//  (bracketing the grid-curve minimum: 768 -> 50.8-52.3us, 1024 -> 64, 1563 -> 71).
//  512 = 2 blocks/CU: -33% weight prologues vs -1 resident block of latency
//  hiding. Binary-identical gemm kernel; zero codegen risk.
// GATHER GRID: 2048 (single dispatch wave, R18: -3.6us total vs 4096).
// LAW (6x replicated: R5=116, R6=162, R8=82, R9=127, R10=166 vs R7/R11/R12=61-64):
//  gemm_fused codegen is on a cliff. ANY in-loop edit spills and 1.4-2.7x's it.
//  Do not edit gemm_fused's body. Launch params are safe (binary unchanged).
// GATHER LAWS: edge padding refuted (R14, +21us); act-split neutral (R15).

typedef __bf16 bf16;
typedef __bf16 bf16x2 __attribute__((ext_vector_type(2)));
typedef __bf16 bf16x4 __attribute__((ext_vector_type(4)));
typedef __bf16 bf16x8 __attribute__((ext_vector_type(8)));
typedef float  f32x4  __attribute__((ext_vector_type(4)));

static inline size_t alignup(size_t x){ return (x + 255) & ~(size_t)255; }

// ---------------- prep: init (cnt/colstats/pooledh) + wc/wprep + gstart ----------------
__global__ void prep_kernel(int* __restrict__ cnt, int N, float* __restrict__ colstats,
                            float* __restrict__ pooledh, int GP, int nb,
                            const float* __restrict__ W1, const float* __restrict__ b1,
                            const float* __restrict__ W2, const float* __restrict__ b2,
                            float* __restrict__ Wc, float* __restrict__ bc,
                            const float* __restrict__ Wl, const float* __restrict__ Wr,
                            bf16* __restrict__ Wbig,
                            const int* __restrict__ batch, int* __restrict__ gstart){
  const int b = blockIdx.x;
  if (b < nb){
    int i = b*256 + threadIdx.x;
    if (i < N) cnt[i] = 0;
    if (i < 768) colstats[i] = 0.f;
    if (i < GP) pooledh[i] = 0.f;
    if (b == 0 && threadIdx.x < 65){   // gstart[g] = lower_bound(batch, g)
      int g = threadIdx.x;
      int lo = 0, hi = N;
      while (lo < hi){ int m = (lo + hi) >> 1; if (batch[m] < g) lo = m + 1; else hi = m; }
      gstart[g] = lo;
    }
  } else if (b < nb + 40){
    int o = b - nb;            // 0..39
    int k = threadIdx.x;       // 256 threads, upper half idles through barriers
    __shared__ float r[128];
    if (k < 128){
      float s = 0.0f;
      for (int j = 0; j < 128; ++j) s = fmaf(W2[o*128 + j], W1[j*128 + k], s);
      Wc[o*128 + k] = s;
      r[k] = W2[o*128 + k] * b1[k];
    }
    __syncthreads();
    for (int off = 64; off; off >>= 1){
      if (k < off) r[k] += r[k + off];
      __syncthreads();
    }
    if (k == 0) bc[o] = r[0] + b2[o];
  } else {
    int idx = (b - nb - 40)*256 + threadIdx.x;
    if (idx < 3*128*256){
      int l = idx / 32768, rem = idx % 32768, c = rem >> 8, k = rem & 255;
      float w = (k < 128) ? Wl[l*16384 + c*128 + k] : Wr[l*16384 + c*128 + (k-128)];
      Wbig[idx] = (bf16)w;
    }
  }
}

// ---------------- fused: edge count (CSR) + x->bf16 ----------------
__global__ void count_xbf_kernel(const int* __restrict__ ei, int E, int* __restrict__ cnt, int eb,
                                 const float* __restrict__ x, bf16* __restrict__ xb, int total8){
  if (blockIdx.x < eb){
    int e = blockIdx.x*256 + threadIdx.x;
    if (e < E) atomicAdd(&cnt[ei[E + e]], 1);   // dst row
  } else {
    int i = (blockIdx.x - eb)*256 + threadIdx.x;
    if (i < total8){
      float4 a = *(const float4*)(x + (size_t)i*8);
      float4 b = *(const float4*)(x + (size_t)i*8 + 4);
      bf16x8 o;
      o[0]=(bf16)a.x; o[1]=(bf16)a.y; o[2]=(bf16)a.z; o[3]=(bf16)a.w;
      o[4]=(bf16)b.x; o[5]=(bf16)b.y; o[6]=(bf16)b.z; o[7]=(bf16)b.w;
      *(bf16x8*)(xb + (size_t)i*8) = o;
    }
  }
}

__global__ void scan1_kernel(const int* __restrict__ cnt, int* __restrict__ rs,
                             int* __restrict__ bsum, int N){
  __shared__ int s[256];
  int t = threadIdx.x;
  int i = blockIdx.x*256 + t;
  int v = (i < N) ? cnt[i] : 0;
  s[t] = v; __syncthreads();
  for (int off = 1; off < 256; off <<= 1){
    int x = (t >= off) ? s[t-off] : 0;
    __syncthreads();
    s[t] += x;
    __syncthreads();
  }
  if (i < N) rs[i] = s[t] - v;
  if (t == 255) bsum[blockIdx.x] = s[255];
}

__global__ void scan2_kernel(int* __restrict__ bsum, int NB){
  __shared__ int s[512];
  int t = threadIdx.x;
  int v = (t < NB) ? bsum[t] : 0;
  s[t] = v; __syncthreads();
  for (int off = 1; off < 512; off <<= 1){
    int x = (t >= off) ? s[t-off] : 0;
    __syncthreads();
    s[t] += x;
    __syncthreads();
  }
  if (t < NB) bsum[t] = s[t] - v;
}

__global__ void scan3_kernel(int* __restrict__ rs, const int* __restrict__ bsum,
                             int* __restrict__ cur, int N){
  int i = blockIdx.x*256 + threadIdx.x;
  if (i < N){
    int v = rs[i] + bsum[blockIdx.x];
    rs[i] = v;
    cur[i] = v;
  }
}

__global__ void fill_kernel(const int* __restrict__ ei, int E, int* __restrict__ cur,
                            int* __restrict__ esrc){
  int e = blockIdx.x*256 + threadIdx.x;
  if (e < E){
    int d = ei[E + e];
    int p = atomicAdd(&cur[d], 1);
    esrc[p] = ei[e];
  }
}

// ---------------- gather: aggx[n] = mean_{j in N(n)} act(h[j]); BN affine computed
// inline from colstats(l-1); block 0 publishes bnp for gemm's staging act.
__global__ __launch_bounds__(256) void gather_kernel(
    const bf16* __restrict__ hsrc, const float* __restrict__ cs,
    const float* __restrict__ gamma, const float* __restrict__ beta,
    float* __restrict__ bnp, float Nf, int use_act,
    const int* __restrict__ rs, const int* __restrict__ cnt, const int* __restrict__ esrc,
    bf16* __restrict__ aggx, int N)
{
  const int t = threadIdx.x;
  const int lane = t & 63;
  const int q  = lane >> 4;    // node slot 0..3 in wave
  const int ql = lane & 15;    // 16B segment owner within row
  const int wid = (blockIdx.x * 256 + t) >> 6;
  const int nw = (gridDim.x * 256) >> 6;
  float sc[8], sh[8];
  if (use_act){
    #pragma unroll
    for (int j = 0; j < 8; ++j){
      const int c = ql*8 + j;
      float mu  = cs[c] / Nf;
      float var = fmaxf(cs[128 + c] / Nf - mu*mu, 0.0f);
      float s   = gamma[c] * rsqrtf(var + 1e-5f);
      sc[j] = s; sh[j] = beta[c] - mu * s;
    }
    if (blockIdx.x == 0 && t < 128){   // publish bnp for gemm staging (read after this kernel)
      float mu  = cs[t] / Nf;
      float var = fmaxf(cs[128 + t] / Nf - mu*mu, 0.0f);
      float s   = gamma[t] * rsqrtf(var + 1e-5f);
      bnp[t] = s;
      bnp[128 + t] = beta[t] - mu * s;
    }
  }
  const int ngrp = N >> 2;   // N divisible by 4
  for (int p = wid; p < ngrp; p += nw){
    const int n = p*4 + q;
    const int start = rs[n];
    const int c = cnt[n];
    float a[8];
    #pragma unroll
    for (int j = 0; j < 8; ++j) a[j] = 0.f;
    int done = 0;
    while (done < c){
      int cc = min(c - done, 16);
      int my = (ql < cc) ? esrc[start + done + ql] : 0;
      int e = 0;
      for (; e + 4 <= cc; e += 4){
        int i0 = __shfl(my, q*16 + e);
        int i1 = __shfl(my, q*16 + e + 1);
        int i2 = __shfl(my, q*16 + e + 2);
        int i3 = __shfl(my, q*16 + e + 3);
        bf16x8 v0 = *(const bf16x8*)(hsrc + (size_t)i0*128 + ql*8);
        bf16x8 v1 = *(const bf16x8*)(hsrc + (size_t)i1*128 + ql*8);
        bf16x8 v2 = *(const bf16x8*)(hsrc + (size_t)i2*128 + ql*8);
        bf16x8 v3 = *(const bf16x8*)(hsrc + (size_t)i3*128 + ql*8);
        if (use_act){
          #pragma unroll
          for (int j = 0; j < 8; ++j){
            a[j] += fmaxf(fmaf((float)v0[j], sc[j], sh[j]), 0.f)
                  + fmaxf(fmaf((float)v1[j], sc[j], sh[j]), 0.f)
                  + fmaxf(fmaf((float)v2[j], sc[j], sh[j]), 0.f)
                  + fmaxf(fmaf((float)v3[j], sc[j], sh[j]), 0.f);
          }
        } else {
          #pragma unroll
          for (int j = 0; j < 8; ++j)
            a[j] += (float)v0[j] + (float)v1[j] + (float)v2[j] + (float)v3[j];
        }
      }
      for (; e < cc; ++e){
        int i0 = __shfl(my, q*16 + e);
        bf16x8 v0 = *(const bf16x8*)(hsrc + (size_t)i0*128 + ql*8);
        if (use_act){
          #pragma unroll
          for (int j = 0; j < 8; ++j)
            a[j] += fmaxf(fmaf((float)v0[j], sc[j], sh[j]), 0.f);
        } else {
          #pragma unroll
          for (int j = 0; j < 8; ++j) a[j] += (float)v0[j];
        }
      }
      done += cc;
    }
    float inv = 1.0f / (float)max(c, 1);
    bf16x8 o;
    #pragma unroll
    for (int j = 0; j < 8; ++j) o[j] = (bf16)(a[j] * inv);
    *(bf16x8*)(aggx + (size_t)n*128 + ql*8) = o;
  }
}

// ---------------- fused GEMM K=256: h2 = [act(h)|aggx] @ [Wl;Wr]^T + bl + br (br dropped deg-0),
// then per-row L2-normalize, store bf16, accumulate BN column stats. W in VGPRs.
// FROZEN at R7 shape — do not edit (see LAW at top).
__global__ __launch_bounds__(256, 3) void gemm_fused(
    const bf16* __restrict__ hin, const bf16* __restrict__ aggx,
    const float* __restrict__ bnp, int use_act,
    const bf16* __restrict__ Wbig, const float* __restrict__ bl, const float* __restrict__ br,
    const int* __restrict__ cnt, bf16* __restrict__ hout, float* __restrict__ colstats, int N)
{
  __shared__ bf16 alds[32*256];    // 16 KB, XOR-swizzled 16B chunks
  __shared__ float rowsq[32];
  __shared__ float colsum[128];
  __shared__ float colsq[128];
  const int t = threadIdx.x;
  const int wv = t >> 6, lane = t & 63;
  const int quad = lane >> 4, l16 = lane & 15;
  const int cbase = wv * 32;

  bf16x8 wreg[2][8];
  #pragma unroll
  for (int nt = 0; nt < 2; ++nt){
    const bf16* wp = Wbig + (size_t)(cbase + nt*16 + l16) * 256 + quad*8;
    #pragma unroll
    for (int ks = 0; ks < 8; ++ks)
      wreg[nt][ks] = *(const bf16x8*)(wp + ks*32);
  }
  float biasv[2][4], brv[2][4];
  #pragma unroll
  for (int nt = 0; nt < 2; ++nt){
    int c0 = cbase + nt*16 + quad*4;
    float4 b4 = *(const float4*)(bl + c0);
    float4 r4 = *(const float4*)(br + c0);
    biasv[nt][0] = b4.x + r4.x; biasv[nt][1] = b4.y + r4.y;
    biasv[nt][2] = b4.z + r4.z; biasv[nt][3] = b4.w + r4.w;
    brv[nt][0] = r4.x; brv[nt][1] = r4.y; brv[nt][2] = r4.z; brv[nt][3] = r4.w;
  }
  if (t < 128){ colsum[t] = 0.f; colsq[t] = 0.f; }

  // staging geometry: linear 16B chunk c = j*256 + t -> row = j*8 + (t>>5),
  // k = t&31 (fixed per thread). k<16: hin (+act), k>=16: aggx. Per load instr,
  // a wave covers two contiguous 512B rows (full cacheline use).
  const int kseg = t & 31;
  const int rowoff = t >> 5;     // 0..7
  float scv[8], shv[8];
  if (use_act && kseg < 16){
    *(float4*)(scv)   = *(const float4*)(bnp + kseg*8);
    *(float4*)(scv+4) = *(const float4*)(bnp + kseg*8 + 4);
    *(float4*)(shv)   = *(const float4*)(bnp + 128 + kseg*8);
    *(float4*)(shv+4) = *(const float4*)(bnp + 128 + kseg*8 + 4);
  }
  const int lds_off = (kseg ^ rowoff) * 8;   // row&7 == rowoff

  const int ntiles = N >> 5;   // N % 32 == 0
  for (int tile = blockIdx.x; tile < ntiles; tile += gridDim.x){
    const int rbase = tile << 5;
    __syncthreads();
    if (t < 32) rowsq[t] = 0.f;
    {
      bf16x8 v[4];
      #pragma unroll
      for (int j = 0; j < 4; ++j){
        const int grow = rbase + j*8 + rowoff;
        if (kseg < 16){
          v[j] = *(const bf16x8*)(hin + (size_t)grow*128 + kseg*8);
          if (use_act){
            #pragma unroll
            for (int qq = 0; qq < 8; ++qq)
              v[j][qq] = (bf16)fmaxf(fmaf((float)v[j][qq], scv[qq], shv[qq]), 0.0f);
          }
        } else {
          v[j] = *(const bf16x8*)(aggx + (size_t)grow*128 + (kseg - 16)*8);
        }
      }
      #pragma unroll
      for (int j = 0; j < 4; ++j)
        *(bf16x8*)(alds + (j*8 + rowoff)*256 + lds_off) = v[j];
    }
    __syncthreads();
    f32x4 acc[2][2];
    #pragma unroll
    for (int mt = 0; mt < 2; ++mt)
      #pragma unroll
      for (int nt = 0; nt < 2; ++nt)
        #pragma unroll
        for (int r = 0; r < 4; ++r) acc[mt][nt][r] = biasv[nt][r];
    #pragma unroll
    for (int ks = 0; ks < 8; ++ks){
      const int ch = ((ks*4 + quad) ^ (l16 & 7)) * 8;
      bf16x8 af0 = *(const bf16x8*)(alds + l16*256 + ch);
      bf16x8 af1 = *(const bf16x8*)(alds + (l16 + 16)*256 + ch);
      acc[0][0] = __builtin_amdgcn_mfma_f32_16x16x32_bf16(wreg[0][ks], af0, acc[0][0], 0, 0, 0);
      acc[0][1] = __builtin_amdgcn_mfma_f32_16x16x32_bf16(wreg[1][ks], af0, acc[0][1], 0, 0, 0);
      acc[1][0] = __builtin_amdgcn_mfma_f32_16x16x32_bf16(wreg[0][ks], af1, acc[1][0], 0, 0, 0);
      acc[1][1] = __builtin_amdgcn_mfma_f32_16x16x32_bf16(wreg[1][ks], af1, acc[1][1], 0, 0, 0);
    }
    const int grow0 = rbase + l16;
    const int grow1 = grow0 + 16;
    const bool v0 = grow0 < N, v1 = grow1 < N;
    const int c0 = v0 ? cnt[grow0] : 1;
    const int c1 = v1 ? cnt[grow1] : 1;
    if (c0 == 0){
      #pragma unroll
      for (int nt = 0; nt < 2; ++nt)
        #pragma unroll
        for (int r = 0; r < 4; ++r) acc[0][nt][r] -= brv[nt][r];
    }
    if (c1 == 0){
      #pragma unroll
      for (int nt = 0; nt < 2; ++nt)
        #pragma unroll
        for (int r = 0; r < 4; ++r) acc[1][nt][r] -= brv[nt][r];
    }
    float s0 = 0.f, s1 = 0.f;
    #pragma unroll
    for (int nt = 0; nt < 2; ++nt)
      #pragma unroll
      for (int r = 0; r < 4; ++r){
        s0 += acc[0][nt][r] * acc[0][nt][r];
        s1 += acc[1][nt][r] * acc[1][nt][r];
      }
    s0 += __shfl_xor(s0, 16); s0 += __shfl_xor(s0, 32);
    s1 += __shfl_xor(s1, 16); s1 += __shfl_xor(s1, 32);
    if (quad == 0){
      atomicAdd(&rowsq[l16], s0);
      atomicAdd(&rowsq[l16 + 16], s1);
    }
    __syncthreads();
    const float scl0 = 1.0f / fmaxf(sqrtf(rowsq[l16]), 1e-12f);
    const float scl1 = 1.0f / fmaxf(sqrtf(rowsq[l16 + 16]), 1e-12f);
    float cs[2][4], cq[2][4];
    #pragma unroll
    for (int nt = 0; nt < 2; ++nt){
      const int col = cbase + nt*16 + quad*4;
      bf16x4 o0, o1;
      #pragma unroll
      for (int r = 0; r < 4; ++r){
        float x0 = acc[0][nt][r] * scl0;
        float x1 = acc[1][nt][r] * scl1;
        o0[r] = (bf16)x0; o1[r] = (bf16)x1;
        float m0 = v0 ? x0 : 0.f;
        float m1 = v1 ? x1 : 0.f;
        cs[nt][r] = m0 + m1;
        cq[nt][r] = m0*m0 + m1*m1;
      }
      if (v0) *(bf16x4*)(hout + (size_t)grow0*128 + col) = o0;
      if (v1) *(bf16x4*)(hout + (size_t)grow1*128 + col) = o1;
    }
    #pragma unroll
    for (int nt = 0; nt < 2; ++nt)
      #pragma unroll
      for (int r = 0; r < 4; ++r){
        float a = cs[nt][r], b = cq[nt][r];
        #pragma unroll
        for (int off = 1; off < 16; off <<= 1){
          a += __shfl_xor(a, off);
          b += __shfl_xor(b, off);
        }
        cs[nt][r] = a; cq[nt][r] = b;
      }
    if (l16 == 0){
      #pragma unroll
      for (int nt = 0; nt < 2; ++nt){
        const int col = cbase + nt*16 + quad*4;
        #pragma unroll
        for (int r = 0; r < 4; ++r){
          atomicAdd(&colsum[col + r], cs[nt][r]);
          atomicAdd(&colsq[col + r], cq[nt][r]);
        }
      }
    }
  }
  __syncthreads();
  if (t < 128){
    atomicAdd(&colstats[t], colsum[t]);
    atomicAdd(&colstats[128 + t], colsq[t]);
  }
}

// ---------------- pool act(h) per graph: graph-sliced, bf16x8 loads, LDS reduce ----------------
__global__ __launch_bounds__(256) void poolh_kernel(
    const bf16* __restrict__ h, const float* __restrict__ cs,
    const float* __restrict__ gamma, const float* __restrict__ beta, float Nf,
    const int* __restrict__ gstart, float* __restrict__ pooledh, int nslice)
{
  const int g  = blockIdx.x / nslice;
  const int sl = blockIdx.x % nslice;
  const int t  = threadIdx.x;
  const int colseg = t & 15;     // 16B segment (8 cols)
  const int rowgrp = t >> 4;     // 0..15
  float sc[8], sh[8];
  #pragma unroll
  for (int j = 0; j < 8; ++j){
    const int c = colseg*8 + j;
    float mu  = cs[c] / Nf;
    float var = fmaxf(cs[128 + c] / Nf - mu*mu, 0.0f);
    float s   = gamma[c] * rsqrtf(var + 1e-5f);
    sc[j] = s; sh[j] = beta[c] - mu * s;
  }
  const int lo = gstart[g], hi = gstart[g + 1];
  const int per = (hi - lo + nslice - 1) / nslice;
  const int rlo = lo + sl*per;
  const int rhi = min(hi, rlo + per);
  float acc[8];
  #pragma unroll
  for (int j = 0; j < 8; ++j) acc[j] = 0.f;
  for (int n = rlo + rowgrp; n < rhi; n += 16){
    bf16x8 v = *(const bf16x8*)(h + (size_t)n*128 + colseg*8);
    #pragma unroll
    for (int j = 0; j < 8; ++j)
      acc[j] += fmaxf(fmaf((float)v[j], sc[j], sh[j]), 0.f);
  }
  __shared__ float red[16][128];
  #pragma unroll
  for (int j = 0; j < 8; ++j) red[rowgrp][colseg*8 + j] = acc[j];
  __syncthreads();
  if (t < 128){
    float s = 0.f;
    #pragma unroll
    for (int r = 0; r < 16; ++r) s += red[r][t];
    atomicAdd(&pooledh[g*128 + t], s);
  }
}

// ---------------- final: out[g] = log_softmax(pooledh[g] @ Wc^T + cnt_g*bc) ----------------
__global__ void lsm_kernel(const float* __restrict__ ph, const float* __restrict__ Wc,
                           const float* __restrict__ bc, const int* __restrict__ gstart,
                           float* __restrict__ out)
{
  const int g = blockIdx.x;
  const int t = threadIdx.x;   // 64 threads = one wave
  const int cntg = gstart[g + 1] - gstart[g];
  float z = -3.0e38f;
  if (t < 40){
    float s = (float)cntg * bc[t];
    const float* phg = ph + g*128;
    const float* w = Wc + t*128;
    for (int k = 0; k < 128; k += 4){
      float4 a = *(const float4*)(phg + k);
      float4 b = *(const float4*)(w + k);
      s = fmaf(a.x, b.x, s); s = fmaf(a.y, b.y, s);
      s = fmaf(a.z, b.z, s); s = fmaf(a.w, b.w, s);
    }
    z = s;
  }
  float mx = z;
  #pragma unroll
  for (int off = 32; off; off >>= 1) mx = fmaxf(mx, __shfl_xor(mx, off));
  float ex = (t < 40) ? expf(z - mx) : 0.0f;
  float sum = ex;
  #pragma unroll
  for (int off = 32; off; off >>= 1) sum += __shfl_xor(sum, off);
  float lse = mx + logf(sum);
  if (t < 40) out[g*40 + t] = z - lse;
}

extern "C" void kernel_launch(void* const* d_in, const int* in_sizes, int n_in,
                              void* d_out, int out_size, void* d_ws, size_t ws_size,
                              hipStream_t stream)
{
  const float* x    = (const float*)d_in[0];
  const int*   ei   = (const int*)d_in[1];
  const int*   batch= (const int*)d_in[2];
  const float* Wl   = (const float*)d_in[3];
  const float* bl   = (const float*)d_in[4];
  const float* Wr   = (const float*)d_in[5];
  const float* br   = (const float*)d_in[6];
  const float* gamma= (const float*)d_in[7];
  const float* beta = (const float*)d_in[8];
  const float* W1   = (const float*)d_in[9];
  const float* b1   = (const float*)d_in[10];
  const float* W2   = (const float*)d_in[11];
  const float* b2   = (const float*)d_in[12];
  float* out = (float*)d_out;

  const int N = in_sizes[0] / 128;
  const int E = in_sizes[1] / 2;
  const int G = out_size / 40;

  char* p = (char*)d_ws;
  auto carve = [&](size_t bytes)->char*{ char* r = p; p += alignup(bytes); return r; };
  bf16*  xbf      = (bf16*)carve((size_t)N * 128 * 2);
  bf16*  aggx     = (bf16*)carve((size_t)N * 128 * 2);
  bf16*  hbuf     = (bf16*)carve((size_t)N * 128 * 2);
  int*   esrc     = (int*)carve((size_t)E * 4);
  int*   rs       = (int*)carve((size_t)N * 4);
  int*   cnt      = (int*)carve((size_t)N * 4);
  int*   cur      = (int*)carve((size_t)N * 4);
  int*   bsum     = (int*)carve(512 * 4);
  float* colstats = (float*)carve(3 * 256 * 4);   // per-layer slices
  float* bnp      = (float*)carve(256 * 4);
  float* Wc       = (float*)carve(40 * 128 * 4);
  float* bc       = (float*)carve(40 * 4);
  bf16*  Wbig     = (bf16*)carve((size_t)3 * 128 * 256 * 2);
  float* pooledh  = (float*)carve((size_t)G * 128 * 4);
  int*   gstart   = (int*)carve(65 * 4);

  const int eb = (E + 255) / 256;
  const int nb = (N + 255) / 256;
  const int xb8 = (N*16 + 255) / 256;
  const int wpb = (3*128*256 + 255) / 256;

  prep_kernel<<<nb + 40 + wpb, 256, 0, stream>>>(cnt, N, colstats, pooledh, G*128, nb,
                                                 W1, b1, W2, b2, Wc, bc, Wl, Wr, Wbig,
                                                 batch, gstart);
  count_xbf_kernel<<<eb + xb8, 256, 0, stream>>>(ei, E, cnt, eb, x, xbf, N*16);
  scan1_kernel<<<nb, 256, 0, stream>>>(cnt, rs, bsum, N);
  scan2_kernel<<<1, 512, 0, stream>>>(bsum, nb);
  scan3_kernel<<<nb, 256, 0, stream>>>(rs, bsum, cur, N);
  fill_kernel<<<eb, 256, 0, stream>>>(ei, E, cur, esrc);

  const float Nf = (float)N;
  for (int l = 0; l < 3; ++l){
    const bf16* hin = (l == 0) ? xbf : hbuf;
    const float* csl = colstats + (l > 0 ? (l-1)*256 : 0);
    const float* gml = gamma + (l > 0 ? (l-1)*128 : 0);
    const float* btl = beta  + (l > 0 ? (l-1)*128 : 0);
    gather_kernel<<<2048, 256, 0, stream>>>(hin, csl, gml, btl, bnp, Nf, (l > 0) ? 1 : 0,
                                            rs, cnt, esrc, aggx, N);
    gemm_fused<<<512, 256, 0, stream>>>(hin, aggx, bnp, (l > 0) ? 1 : 0,
                                        Wbig + (size_t)l * 32768, bl + l*128, br + l*128,
                                        cnt, hbuf, colstats + l*256, N);
  }
  const int nslice = 8;
  poolh_kernel<<<G * nslice, 256, 0, stream>>>(hbuf, colstats + 2*256, gamma + 2*128,
                                               beta + 2*128, Nf, gstart, pooledh, nslice);
  lsm_kernel<<<G, 64, 0, stream>>>(pooledh, Wc, bc, gstart, out);
}

// Round 16
// 425.691 us; speedup vs baseline: 1.0301x; 1.0301x over previous
//
#include <hip/hip_runtime.h>
#include <math.h>

// GraphSage GNN forward. N=100000 (div 32), E=600000, HID=128, OUT=40, G=64, L=3.
// R20 = R18 EXACTLY (best measured: 426.2us) — reverting R19's gemm grid 512.
// GEMM GRID CURVE (measured, minimum bracketed): 512 -> 53.7us, 768 -> 50.8,
//  1024 -> 64, 1563 -> 71. OPTIMUM = 768 (exactly 3 blocks/CU; balance of
//  per-block 64KB weight-prologue count vs resident latency-hiding).
// GATHER GRID: 2048 (single dispatch wave; R18 measured -3.6us vs 4096).
// LAW (6x replicated: R5=116, R6=162, R8=82, R9=127, R10=166 vs R7/R11/R12=61-64):
//  gemm_fused codegen is on a cliff. ANY in-loop edit spills and 1.4-2.7x's it.
//  Do not edit gemm_fused's body. Launch params are safe (binary unchanged).
// GATHER LAWS: edge padding refuted (R14, +21us); act-split neutral (R15).
//  gather ~55us is latency-bound on L3-random 256B row reads.

typedef __bf16 bf16;
typedef __bf16 bf16x2 __attribute__((ext_vector_type(2)));
typedef __bf16 bf16x4 __attribute__((ext_vector_type(4)));
typedef __bf16 bf16x8 __attribute__((ext_vector_type(8)));
typedef float  f32x4  __attribute__((ext_vector_type(4)));

static inline size_t alignup(size_t x){ return (x + 255) & ~(size_t)255; }

// ---------------- prep: init (cnt/colstats/pooledh) + wc/wprep + gstart ----------------
__global__ void prep_kernel(int* __restrict__ cnt, int N, float* __restrict__ colstats,
                            float* __restrict__ pooledh, int GP, int nb,
                            const float* __restrict__ W1, const float* __restrict__ b1,
                            const float* __restrict__ W2, const float* __restrict__ b2,
                            float* __restrict__ Wc, float* __restrict__ bc,
                            const float* __restrict__ Wl, const float* __restrict__ Wr,
                            bf16* __restrict__ Wbig,
                            const int* __restrict__ batch, int* __restrict__ gstart){
  const int b = blockIdx.x;
  if (b < nb){
    int i = b*256 + threadIdx.x;
    if (i < N) cnt[i] = 0;
    if (i < 768) colstats[i] = 0.f;
    if (i < GP) pooledh[i] = 0.f;
    if (b == 0 && threadIdx.x < 65){   // gstart[g] = lower_bound(batch, g)
      int g = threadIdx.x;
      int lo = 0, hi = N;
      while (lo < hi){ int m = (lo + hi) >> 1; if (batch[m] < g) lo = m + 1; else hi = m; }
      gstart[g] = lo;
    }
  } else if (b < nb + 40){
    int o = b - nb;            // 0..39
    int k = threadIdx.x;       // 256 threads, upper half idles through barriers
    __shared__ float r[128];
    if (k < 128){
      float s = 0.0f;
      for (int j = 0; j < 128; ++j) s = fmaf(W2[o*128 + j], W1[j*128 + k], s);
      Wc[o*128 + k] = s;
      r[k] = W2[o*128 + k] * b1[k];
    }
    __syncthreads();
    for (int off = 64; off; off >>= 1){
      if (k < off) r[k] += r[k + off];
      __syncthreads();
    }
    if (k == 0) bc[o] = r[0] + b2[o];
  } else {
    int idx = (b - nb - 40)*256 + threadIdx.x;
    if (idx < 3*128*256){
      int l = idx / 32768, rem = idx % 32768, c = rem >> 8, k = rem & 255;
      float w = (k < 128) ? Wl[l*16384 + c*128 + k] : Wr[l*16384 + c*128 + (k-128)];
      Wbig[idx] = (bf16)w;
    }
  }
}

// ---------------- fused: edge count (CSR) + x->bf16 ----------------
__global__ void count_xbf_kernel(const int* __restrict__ ei, int E, int* __restrict__ cnt, int eb,
                                 const float* __restrict__ x, bf16* __restrict__ xb, int total8){
  if (blockIdx.x < eb){
    int e = blockIdx.x*256 + threadIdx.x;
    if (e < E) atomicAdd(&cnt[ei[E + e]], 1);   // dst row
  } else {
    int i = (blockIdx.x - eb)*256 + threadIdx.x;
    if (i < total8){
      float4 a = *(const float4*)(x + (size_t)i*8);
      float4 b = *(const float4*)(x + (size_t)i*8 + 4);
      bf16x8 o;
      o[0]=(bf16)a.x; o[1]=(bf16)a.y; o[2]=(bf16)a.z; o[3]=(bf16)a.w;
      o[4]=(bf16)b.x; o[5]=(bf16)b.y; o[6]=(bf16)b.z; o[7]=(bf16)b.w;
      *(bf16x8*)(xb + (size_t)i*8) = o;
    }
  }
}

__global__ void scan1_kernel(const int* __restrict__ cnt, int* __restrict__ rs,
                             int* __restrict__ bsum, int N){
  __shared__ int s[256];
  int t = threadIdx.x;
  int i = blockIdx.x*256 + t;
  int v = (i < N) ? cnt[i] : 0;
  s[t] = v; __syncthreads();
  for (int off = 1; off < 256; off <<= 1){
    int x = (t >= off) ? s[t-off] : 0;
    __syncthreads();
    s[t] += x;
    __syncthreads();
  }
  if (i < N) rs[i] = s[t] - v;
  if (t == 255) bsum[blockIdx.x] = s[255];
}

__global__ void scan2_kernel(int* __restrict__ bsum, int NB){
  __shared__ int s[512];
  int t = threadIdx.x;
  int v = (t < NB) ? bsum[t] : 0;
  s[t] = v; __syncthreads();
  for (int off = 1; off < 512; off <<= 1){
    int x = (t >= off) ? s[t-off] : 0;
    __syncthreads();
    s[t] += x;
    __syncthreads();
  }
  if (t < NB) bsum[t] = s[t] - v;
}

__global__ void scan3_kernel(int* __restrict__ rs, const int* __restrict__ bsum,
                             int* __restrict__ cur, int N){
  int i = blockIdx.x*256 + threadIdx.x;
  if (i < N){
    int v = rs[i] + bsum[blockIdx.x];
    rs[i] = v;
    cur[i] = v;
  }
}

__global__ void fill_kernel(const int* __restrict__ ei, int E, int* __restrict__ cur,
                            int* __restrict__ esrc){
  int e = blockIdx.x*256 + threadIdx.x;
  if (e < E){
    int d = ei[E + e];
    int p = atomicAdd(&cur[d], 1);
    esrc[p] = ei[e];
  }
}

// ---------------- gather: aggx[n] = mean_{j in N(n)} act(h[j]); BN affine computed
// inline from colstats(l-1); block 0 publishes bnp for gemm's staging act.
__global__ __launch_bounds__(256) void gather_kernel(
    const bf16* __restrict__ hsrc, const float* __restrict__ cs,
    const float* __restrict__ gamma, const float* __restrict__ beta,
    float* __restrict__ bnp, float Nf, int use_act,
    const int* __restrict__ rs, const int* __restrict__ cnt, const int* __restrict__ esrc,
    bf16* __restrict__ aggx, int N)
{
  const int t = threadIdx.x;
  const int lane = t & 63;
  const int q  = lane >> 4;    // node slot 0..3 in wave
  const int ql = lane & 15;    // 16B segment owner within row
  const int wid = (blockIdx.x * 256 + t) >> 6;
  const int nw = (gridDim.x * 256) >> 6;
  float sc[8], sh[8];
  if (use_act){
    #pragma unroll
    for (int j = 0; j < 8; ++j){
      const int c = ql*8 + j;
      float mu  = cs[c] / Nf;
      float var = fmaxf(cs[128 + c] / Nf - mu*mu, 0.0f);
      float s   = gamma[c] * rsqrtf(var + 1e-5f);
      sc[j] = s; sh[j] = beta[c] - mu * s;
    }
    if (blockIdx.x == 0 && t < 128){   // publish bnp for gemm staging (read after this kernel)
      float mu  = cs[t] / Nf;
      float var = fmaxf(cs[128 + t] / Nf - mu*mu, 0.0f);
      float s   = gamma[t] * rsqrtf(var + 1e-5f);
      bnp[t] = s;
      bnp[128 + t] = beta[t] - mu * s;
    }
  }
  const int ngrp = N >> 2;   // N divisible by 4
  for (int p = wid; p < ngrp; p += nw){
    const int n = p*4 + q;
    const int start = rs[n];
    const int c = cnt[n];
    float a[8];
    #pragma unroll
    for (int j = 0; j < 8; ++j) a[j] = 0.f;
    int done = 0;
    while (done < c){
      int cc = min(c - done, 16);
      int my = (ql < cc) ? esrc[start + done + ql] : 0;
      int e = 0;
      for (; e + 4 <= cc; e += 4){
        int i0 = __shfl(my, q*16 + e);
        int i1 = __shfl(my, q*16 + e + 1);
        int i2 = __shfl(my, q*16 + e + 2);
        int i3 = __shfl(my, q*16 + e + 3);
        bf16x8 v0 = *(const bf16x8*)(hsrc + (size_t)i0*128 + ql*8);
        bf16x8 v1 = *(const bf16x8*)(hsrc + (size_t)i1*128 + ql*8);
        bf16x8 v2 = *(const bf16x8*)(hsrc + (size_t)i2*128 + ql*8);
        bf16x8 v3 = *(const bf16x8*)(hsrc + (size_t)i3*128 + ql*8);
        if (use_act){
          #pragma unroll
          for (int j = 0; j < 8; ++j){
            a[j] += fmaxf(fmaf((float)v0[j], sc[j], sh[j]), 0.f)
                  + fmaxf(fmaf((float)v1[j], sc[j], sh[j]), 0.f)
                  + fmaxf(fmaf((float)v2[j], sc[j], sh[j]), 0.f)
                  + fmaxf(fmaf((float)v3[j], sc[j], sh[j]), 0.f);
          }
        } else {
          #pragma unroll
          for (int j = 0; j < 8; ++j)
            a[j] += (float)v0[j] + (float)v1[j] + (float)v2[j] + (float)v3[j];
        }
      }
      for (; e < cc; ++e){
        int i0 = __shfl(my, q*16 + e);
        bf16x8 v0 = *(const bf16x8*)(hsrc + (size_t)i0*128 + ql*8);
        if (use_act){
          #pragma unroll
          for (int j = 0; j < 8; ++j)
            a[j] += fmaxf(fmaf((float)v0[j], sc[j], sh[j]), 0.f);
        } else {
          #pragma unroll
          for (int j = 0; j < 8; ++j) a[j] += (float)v0[j];
        }
      }
      done += cc;
    }
    float inv = 1.0f / (float)max(c, 1);
    bf16x8 o;
    #pragma unroll
    for (int j = 0; j < 8; ++j) o[j] = (bf16)(a[j] * inv);
    *(bf16x8*)(aggx + (size_t)n*128 + ql*8) = o;
  }
}

// ---------------- fused GEMM K=256: h2 = [act(h)|aggx] @ [Wl;Wr]^T + bl + br (br dropped deg-0),
// then per-row L2-normalize, store bf16, accumulate BN column stats. W in VGPRs.
// FROZEN at R7 shape — do not edit (see LAW at top).
__global__ __launch_bounds__(256, 3) void gemm_fused(
    const bf16* __restrict__ hin, const bf16* __restrict__ aggx,
    const float* __restrict__ bnp, int use_act,
    const bf16* __restrict__ Wbig, const float* __restrict__ bl, const float* __restrict__ br,
    const int* __restrict__ cnt, bf16* __restrict__ hout, float* __restrict__ colstats, int N)
{
  __shared__ bf16 alds[32*256];    // 16 KB, XOR-swizzled 16B chunks
  __shared__ float rowsq[32];
  __shared__ float colsum[128];
  __shared__ float colsq[128];
  const int t = threadIdx.x;
  const int wv = t >> 6, lane = t & 63;
  const int quad = lane >> 4, l16 = lane & 15;
  const int cbase = wv * 32;

  bf16x8 wreg[2][8];
  #pragma unroll
  for (int nt = 0; nt < 2; ++nt){
    const bf16* wp = Wbig + (size_t)(cbase + nt*16 + l16) * 256 + quad*8;
    #pragma unroll
    for (int ks = 0; ks < 8; ++ks)
      wreg[nt][ks] = *(const bf16x8*)(wp + ks*32);
  }
  float biasv[2][4], brv[2][4];
  #pragma unroll
  for (int nt = 0; nt < 2; ++nt){
    int c0 = cbase + nt*16 + quad*4;
    float4 b4 = *(const float4*)(bl + c0);
    float4 r4 = *(const float4*)(br + c0);
    biasv[nt][0] = b4.x + r4.x; biasv[nt][1] = b4.y + r4.y;
    biasv[nt][2] = b4.z + r4.z; biasv[nt][3] = b4.w + r4.w;
    brv[nt][0] = r4.x; brv[nt][1] = r4.y; brv[nt][2] = r4.z; brv[nt][3] = r4.w;
  }
  if (t < 128){ colsum[t] = 0.f; colsq[t] = 0.f; }

  // staging geometry: linear 16B chunk c = j*256 + t -> row = j*8 + (t>>5),
  // k = t&31 (fixed per thread). k<16: hin (+act), k>=16: aggx. Per load instr,
  // a wave covers two contiguous 512B rows (full cacheline use).
  const int kseg = t & 31;
  const int rowoff = t >> 5;     // 0..7
  float scv[8], shv[8];
  if (use_act && kseg < 16){
    *(float4*)(scv)   = *(const float4*)(bnp + kseg*8);
    *(float4*)(scv+4) = *(const float4*)(bnp + kseg*8 + 4);
    *(float4*)(shv)   = *(const float4*)(bnp + 128 + kseg*8);
    *(float4*)(shv+4) = *(const float4*)(bnp + 128 + kseg*8 + 4);
  }
  const int lds_off = (kseg ^ rowoff) * 8;   // row&7 == rowoff

  const int ntiles = N >> 5;   // N % 32 == 0
  for (int tile = blockIdx.x; tile < ntiles; tile += gridDim.x){
    const int rbase = tile << 5;
    __syncthreads();
    if (t < 32) rowsq[t] = 0.f;
    {
      bf16x8 v[4];
      #pragma unroll
      for (int j = 0; j < 4; ++j){
        const int grow = rbase + j*8 + rowoff;
        if (kseg < 16){
          v[j] = *(const bf16x8*)(hin + (size_t)grow*128 + kseg*8);
          if (use_act){
            #pragma unroll
            for (int qq = 0; qq < 8; ++qq)
              v[j][qq] = (bf16)fmaxf(fmaf((float)v[j][qq], scv[qq], shv[qq]), 0.0f);
          }
        } else {
          v[j] = *(const bf16x8*)(aggx + (size_t)grow*128 + (kseg - 16)*8);
        }
      }
      #pragma unroll
      for (int j = 0; j < 4; ++j)
        *(bf16x8*)(alds + (j*8 + rowoff)*256 + lds_off) = v[j];
    }
    __syncthreads();
    f32x4 acc[2][2];
    #pragma unroll
    for (int mt = 0; mt < 2; ++mt)
      #pragma unroll
      for (int nt = 0; nt < 2; ++nt)
        #pragma unroll
        for (int r = 0; r < 4; ++r) acc[mt][nt][r] = biasv[nt][r];
    #pragma unroll
    for (int ks = 0; ks < 8; ++ks){
      const int ch = ((ks*4 + quad) ^ (l16 & 7)) * 8;
      bf16x8 af0 = *(const bf16x8*)(alds + l16*256 + ch);
      bf16x8 af1 = *(const bf16x8*)(alds + (l16 + 16)*256 + ch);
      acc[0][0] = __builtin_amdgcn_mfma_f32_16x16x32_bf16(wreg[0][ks], af0, acc[0][0], 0, 0, 0);
      acc[0][1] = __builtin_amdgcn_mfma_f32_16x16x32_bf16(wreg[1][ks], af0, acc[0][1], 0, 0, 0);
      acc[1][0] = __builtin_amdgcn_mfma_f32_16x16x32_bf16(wreg[0][ks], af1, acc[1][0], 0, 0, 0);
      acc[1][1] = __builtin_amdgcn_mfma_f32_16x16x32_bf16(wreg[1][ks], af1, acc[1][1], 0, 0, 0);
    }
    const int grow0 = rbase + l16;
    const int grow1 = grow0 + 16;
    const bool v0 = grow0 < N, v1 = grow1 < N;
    const int c0 = v0 ? cnt[grow0] : 1;
    const int c1 = v1 ? cnt[grow1] : 1;
    if (c0 == 0){
      #pragma unroll
      for (int nt = 0; nt < 2; ++nt)
        #pragma unroll
        for (int r = 0; r < 4; ++r) acc[0][nt][r] -= brv[nt][r];
    }
    if (c1 == 0){
      #pragma unroll
      for (int nt = 0; nt < 2; ++nt)
        #pragma unroll
        for (int r = 0; r < 4; ++r) acc[1][nt][r] -= brv[nt][r];
    }
    float s0 = 0.f, s1 = 0.f;
    #pragma unroll
    for (int nt = 0; nt < 2; ++nt)
      #pragma unroll
      for (int r = 0; r < 4; ++r){
        s0 += acc[0][nt][r] * acc[0][nt][r];
        s1 += acc[1][nt][r] * acc[1][nt][r];
      }
    s0 += __shfl_xor(s0, 16); s0 += __shfl_xor(s0, 32);
    s1 += __shfl_xor(s1, 16); s1 += __shfl_xor(s1, 32);
    if (quad == 0){
      atomicAdd(&rowsq[l16], s0);
      atomicAdd(&rowsq[l16 + 16], s1);
    }
    __syncthreads();
    const float scl0 = 1.0f / fmaxf(sqrtf(rowsq[l16]), 1e-12f);
    const float scl1 = 1.0f / fmaxf(sqrtf(rowsq[l16 + 16]), 1e-12f);
    float cs[2][4], cq[2][4];
    #pragma unroll
    for (int nt = 0; nt < 2; ++nt){
      const int col = cbase + nt*16 + quad*4;
      bf16x4 o0, o1;
      #pragma unroll
      for (int r = 0; r < 4; ++r){
        float x0 = acc[0][nt][r] * scl0;
        float x1 = acc[1][nt][r] * scl1;
        o0[r] = (bf16)x0; o1[r] = (bf16)x1;
        float m0 = v0 ? x0 : 0.f;
        float m1 = v1 ? x1 : 0.f;
        cs[nt][r] = m0 + m1;
        cq[nt][r] = m0*m0 + m1*m1;
      }
      if (v0) *(bf16x4*)(hout + (size_t)grow0*128 + col) = o0;
      if (v1) *(bf16x4*)(hout + (size_t)grow1*128 + col) = o1;
    }
    #pragma unroll
    for (int nt = 0; nt < 2; ++nt)
      #pragma unroll
      for (int r = 0; r < 4; ++r){
        float a = cs[nt][r], b = cq[nt][r];
        #pragma unroll
        for (int off = 1; off < 16; off <<= 1){
          a += __shfl_xor(a, off);
          b += __shfl_xor(b, off);
        }
        cs[nt][r] = a; cq[nt][r] = b;
      }
    if (l16 == 0){
      #pragma unroll
      for (int nt = 0; nt < 2; ++nt){
        const int col = cbase + nt*16 + quad*4;
        #pragma unroll
        for (int r = 0; r < 4; ++r){
          atomicAdd(&colsum[col + r], cs[nt][r]);
          atomicAdd(&colsq[col + r], cq[nt][r]);
        }
      }
    }
  }
  __syncthreads();
  if (t < 128){
    atomicAdd(&colstats[t], colsum[t]);
    atomicAdd(&colstats[128 + t], colsq[t]);
  }
}

// ---------------- pool act(h) per graph: graph-sliced, bf16x8 loads, LDS reduce ----------------
__global__ __launch_bounds__(256) void poolh_kernel(
    const bf16* __restrict__ h, const float* __restrict__ cs,
    const float* __restrict__ gamma, const float* __restrict__ beta, float Nf,
    const int* __restrict__ gstart, float* __restrict__ pooledh, int nslice)
{
  const int g  = blockIdx.x / nslice;
  const int sl = blockIdx.x % nslice;
  const int t  = threadIdx.x;
  const int colseg = t & 15;     // 16B segment (8 cols)
  const int rowgrp = t >> 4;     // 0..15
  float sc[8], sh[8];
  #pragma unroll
  for (int j = 0; j < 8; ++j){
    const int c = colseg*8 + j;
    float mu  = cs[c] / Nf;
    float var = fmaxf(cs[128 + c] / Nf - mu*mu, 0.0f);
    float s   = gamma[c] * rsqrtf(var + 1e-5f);
    sc[j] = s; sh[j] = beta[c] - mu * s;
  }
  const int lo = gstart[g], hi = gstart[g + 1];
  const int per = (hi - lo + nslice - 1) / nslice;
  const int rlo = lo + sl*per;
  const int rhi = min(hi, rlo + per);
  float acc[8];
  #pragma unroll
  for (int j = 0; j < 8; ++j) acc[j] = 0.f;
  for (int n = rlo + rowgrp; n < rhi; n += 16){
    bf16x8 v = *(const bf16x8*)(h + (size_t)n*128 + colseg*8);
    #pragma unroll
    for (int j = 0; j < 8; ++j)
      acc[j] += fmaxf(fmaf((float)v[j], sc[j], sh[j]), 0.f);
  }
  __shared__ float red[16][128];
  #pragma unroll
  for (int j = 0; j < 8; ++j) red[rowgrp][colseg*8 + j] = acc[j];
  __syncthreads();
  if (t < 128){
    float s = 0.f;
    #pragma unroll
    for (int r = 0; r < 16; ++r) s += red[r][t];
    atomicAdd(&pooledh[g*128 + t], s);
  }
}

// ---------------- final: out[g] = log_softmax(pooledh[g] @ Wc^T + cnt_g*bc) ----------------
__global__ void lsm_kernel(const float* __restrict__ ph, const float* __restrict__ Wc,
                           const float* __restrict__ bc, const int* __restrict__ gstart,
                           float* __restrict__ out)
{
  const int g = blockIdx.x;
  const int t = threadIdx.x;   // 64 threads = one wave
  const int cntg = gstart[g + 1] - gstart[g];
  float z = -3.0e38f;
  if (t < 40){
    float s = (float)cntg * bc[t];
    const float* phg = ph + g*128;
    const float* w = Wc + t*128;
    for (int k = 0; k < 128; k += 4){
      float4 a = *(const float4*)(phg + k);
      float4 b = *(const float4*)(w + k);
      s = fmaf(a.x, b.x, s); s = fmaf(a.y, b.y, s);
      s = fmaf(a.z, b.z, s); s = fmaf(a.w, b.w, s);
    }
    z = s;
  }
  float mx = z;
  #pragma unroll
  for (int off = 32; off; off >>= 1) mx = fmaxf(mx, __shfl_xor(mx, off));
  float ex = (t < 40) ? expf(z - mx) : 0.0f;
  float sum = ex;
  #pragma unroll
  for (int off = 32; off; off >>= 1) sum += __shfl_xor(sum, off);
  float lse = mx + logf(sum);
  if (t < 40) out[g*40 + t] = z - lse;
}

extern "C" void kernel_launch(void* const* d_in, const int* in_sizes, int n_in,
                              void* d_out, int out_size, void* d_ws, size_t ws_size,
                              hipStream_t stream)
{
  const float* x    = (const float*)d_in[0];
  const int*   ei   = (const int*)d_in[1];
  const int*   batch= (const int*)d_in[2];
  const float* Wl   = (const float*)d_in[3];
  const float* bl   = (const float*)d_in[4];
  const float* Wr   = (const float*)d_in[5];
  const float* br   = (const float*)d_in[6];
  const float* gamma= (const float*)d_in[7];
  const float* beta = (const float*)d_in[8];
  const float* W1   = (const float*)d_in[9];
  const float* b1   = (const float*)d_in[10];
  const float* W2   = (const float*)d_in[11];
  const float* b2   = (const float*)d_in[12];
  float* out = (float*)d_out;

  const int N = in_sizes[0] / 128;
  const int E = in_sizes[1] / 2;
  const int G = out_size / 40;

  char* p = (char*)d_ws;
  auto carve = [&](size_t bytes)->char*{ char* r = p; p += alignup(bytes); return r; };
  bf16*  xbf      = (bf16*)carve((size_t)N * 128 * 2);
  bf16*  aggx     = (bf16*)carve((size_t)N * 128 * 2);
  bf16*  hbuf     = (bf16*)carve((size_t)N * 128 * 2);
  int*   esrc     = (int*)carve((size_t)E * 4);
  int*   rs       = (int*)carve((size_t)N * 4);
  int*   cnt      = (int*)carve((size_t)N * 4);
  int*   cur      = (int*)carve((size_t)N * 4);
  int*   bsum     = (int*)carve(512 * 4);
  float* colstats = (float*)carve(3 * 256 * 4);   // per-layer slices
  float* bnp      = (float*)carve(256 * 4);
  float* Wc       = (float*)carve(40 * 128 * 4);
  float* bc       = (float*)carve(40 * 4);
  bf16*  Wbig     = (bf16*)carve((size_t)3 * 128 * 256 * 2);
  float* pooledh  = (float*)carve((size_t)G * 128 * 4);
  int*   gstart   = (int*)carve(65 * 4);

  const int eb = (E + 255) / 256;
  const int nb = (N + 255) / 256;
  const int xb8 = (N*16 + 255) / 256;
  const int wpb = (3*128*256 + 255) / 256;

  prep_kernel<<<nb + 40 + wpb, 256, 0, stream>>>(cnt, N, colstats, pooledh, G*128, nb,
                                                 W1, b1, W2, b2, Wc, bc, Wl, Wr, Wbig,
                                                 batch, gstart);
  count_xbf_kernel<<<eb + xb8, 256, 0, stream>>>(ei, E, cnt, eb, x, xbf, N*16);
  scan1_kernel<<<nb, 256, 0, stream>>>(cnt, rs, bsum, N);
  scan2_kernel<<<1, 512, 0, stream>>>(bsum, nb);
  scan3_kernel<<<nb, 256, 0, stream>>>(rs, cnt ? bsum : bsum, cur, N);
  fill_kernel<<<eb, 256, 0, stream>>>(ei, E, cur, esrc);

  const float Nf = (float)N;
  for (int l = 0; l < 3; ++l){
    const bf16* hin = (l == 0) ? xbf : hbuf;
    const float* csl = colstats + (l > 0 ? (l-1)*256 : 0);
    const float* gml = gamma + (l > 0 ? (l-1)*128 : 0);
    const float* btl = beta  + (l > 0 ? (l-1)*128 : 0);
    gather_kernel<<<2048, 256, 0, stream>>>(hin, csl, gml, btl, bnp, Nf, (l > 0) ? 1 : 0,
                                            rs, cnt, esrc, aggx, N);
    gemm_fused<<<768, 256, 0, stream>>>(hin, aggx, bnp, (l > 0) ? 1 : 0,
                                        Wbig + (size_t)l * 32768, bl + l*128, br + l*128,
                                        cnt, hbuf, colstats + l*256, N);
  }
  const int nslice = 8;
  poolh_kernel<<<G * nslice, 256, 0, stream>>>(hbuf, colstats + 2*256, gamma + 2*128,
                                               beta + 2*128, Nf, gstart, pooledh, nslice);
  lsm_kernel<<<G, 64, 0, stream>>>(pooledh, Wc, bc, gstart, out);
}